// Round 2
// baseline (88055.750 us; speedup 1.0000x reference)
//
#include <hip/hip_runtime.h>
#include <hip/hip_bf16.h>
#include <stdint.h>

typedef unsigned short u16;
typedef float f32x4 __attribute__((ext_vector_type(4)));
typedef __bf16 bf16x8 __attribute__((ext_vector_type(8)));

__device__ inline u16 f2bf(float f) {
  __bf16 h = (__bf16)f;                 // RTNE
  return __builtin_bit_cast(u16, h);
}
__device__ inline float bf2f(u16 u) {
  unsigned int x = ((unsigned int)u) << 16;
  return __builtin_bit_cast(float, x);
}
__device__ inline f32x4 mfma16(bf16x8 a, bf16x8 b, f32x4 c) {
  return __builtin_amdgcn_mfma_f32_16x16x32_bf16(a, b, c, 0, 0, 0);
}
// split 8 contiguous fp32 into bf16 hi + lo fragments
__device__ inline void cvt8(const float* p, bf16x8& h, bf16x8& l) {
  f32x4 u = *(const f32x4*)p;
  f32x4 v = *(const f32x4*)(p + 4);
#pragma unroll
  for (int i = 0; i < 4; ++i) {
    float a = u[i]; __bf16 ah = (__bf16)a; h[i] = ah; l[i] = (__bf16)(a - (float)ah);
    float b = v[i]; __bf16 bh = (__bf16)b; h[i + 4] = bh; l[i + 4] = (__bf16)(b - (float)bh);
  }
}
// gather 8 k-strided fp32 (stride 1024 floats) into bf16 hi + lo fragments
__device__ inline void gather8(const float* p, bf16x8& h, bf16x8& l) {
#pragma unroll
  for (int e = 0; e < 8; ++e) {
    float f = p[(size_t)e * 1024];
    __bf16 x = (__bf16)f;
    h[e] = x; l[e] = (__bf16)(f - (float)x);
  }
}

struct RecArgs {
  const float* x;
  const float *W_ix, *W_ih, *W_ic, *W_fx, *W_fh, *W_fc, *W_cx, *W_ch;
  const float *W_ox, *W_oh, *W_oc;
  const float *b_i, *b_f, *b_c, *b_o;
  u16 *hh, *hl, *ch0, *cl0, *ch1, *cl1;   // state planes [32][1024] bf16
  unsigned* cnt;
  float* out;
};

// grid barrier: monotonic counter, timeout-capped poll (garbage > hang)
__device__ inline void gbar(unsigned* cnt, unsigned target) {
  __syncthreads();
  __threadfence();                                   // release prior stores
  if (threadIdx.x == 0) {
    __hip_atomic_fetch_add(cnt, 1u, __ATOMIC_RELEASE, __HIP_MEMORY_SCOPE_AGENT);
    int it = 0;
    while (__hip_atomic_load(cnt, __ATOMIC_ACQUIRE, __HIP_MEMORY_SCOPE_AGENT) < target
           && it < 40000) {
      __builtin_amdgcn_s_sleep(8);
      ++it;
    }
  }
  __syncthreads();
  __threadfence();                                   // acquire: invalidate stale caches
}

// Persistent LSTM: 256 blocks x 512 threads (8 waves). Block owns 4 H-columns
// of each gate (16 gate-cols). Wave w owns K-slice [w*128, w*128+128).
// All weights register-resident as MFMA B-fragments (hi/lo bf16 split).
// Static LDS: 16KB reduce scratch only. 2 grid barriers per step.
__global__ __launch_bounds__(512, 2) void lstm_rec(RecArgs a) {
  __shared__ float scr[8 * 2 * 16 * 16];   // [wave][mt][row][col]

  const int tid = threadIdx.x;
  const int wg = blockIdx.x;
  const int j0 = wg * 4;
  const int lane = tid & 63;
  const int wave = tid >> 6;
  const int mrow = lane & 15;               // A-row (batch) lane index
  const int kq = (lane >> 4) * 8;           // k sub-offset within 32
  const int kw = wave * 128;                // per-wave K slice
  const int col = lane & 15;                // B/D column lane index
  const int rq = (lane >> 4) * 4;           // D row quad base

  // ---- one-time: B-fragments (weights) -> registers, hi/lo split ----
  const int fjj = col >> 2, fg = col & 3;   // col = jj*4 + g
  const int fj = j0 + fjj;
  const float* Wx = (fg == 0) ? a.W_ix : (fg == 1) ? a.W_fx : (fg == 2) ? a.W_cx : a.W_ox;
  const float* Wh = (fg == 0) ? a.W_ih : (fg == 1) ? a.W_fh : (fg == 2) ? a.W_ch : a.W_oh;
  const float* Wc = (fg == 0) ? a.W_ic : (fg == 1) ? a.W_fc : (fg == 3) ? a.W_oc : a.W_ic;

  bf16x8 bxh[4], bxl[4], bhh[4], bhl[4], bch[4], bcl[4];
#pragma unroll
  for (int ks = 0; ks < 4; ++ks) {
    const size_t k8 = (size_t)(kw + ks * 32 + kq);
    gather8(Wx + k8 * 1024 + fj, bxh[ks], bxl[ks]);
    gather8(Wh + k8 * 1024 + fj, bhh[ks], bhl[ks]);
    if (fg != 2) {
      gather8(Wc + k8 * 1024 + fj, bch[ks], bcl[ks]);
    } else {
      bf16x8 z = {};
      bch[ks] = z; bcl[ks] = z;
    }
  }

  // ---- zero own slice of state ----
  if (tid < 128) {
    const int b = tid >> 2;
    const int o = b * 1024 + j0 + (tid & 3);
    a.hh[o] = 0; a.hl[o] = 0;
    a.ch0[o] = 0; a.cl0[o] = 0; a.ch1[o] = 0; a.cl1[o] = 0;
  }
  unsigned ep = 0;
  gbar(a.cnt, (++ep) * gridDim.x);

  // elementwise thread constants (threads 0..127: b = tid>>2, jj = tid&3)
  const int eb = tid >> 2, ejj = tid & 3, ej = j0 + (tid & 3);
  float bi = 0.f, bfv = 0.f, bcv = 0.f, bo = 0.f;
  if (tid < 128) {
    bi = a.b_i[ej]; bfv = a.b_f[eb * 1024 + ej]; bcv = a.b_c[ej]; bo = a.b_o[ej];
  }
  float c_reg = 0.f, o_pre = 0.f;

  u16* CH[2] = {a.ch0, a.ch1};
  u16* CL[2] = {a.cl0, a.cl1};

  for (int t = 0; t < 512; ++t) {
    u16* chc = CH[t & 1];       u16* clc = CL[t & 1];
    const u16* chp = CH[(t & 1) ^ 1];
    const u16* clp = CL[(t & 1) ^ 1];

    // ======== phase 1: pre-gates = x@Wx + h@Wh (+ c@Wc peephole i,f) ========
    f32x4 acc0 = {}, acc1 = {}, pc0 = {}, pc1 = {};
#pragma unroll
    for (int ks = 0; ks < 4; ++ks) {
      const int ka = kw + ks * 32 + kq;
      // A fragments
      bf16x8 xh0, xl0, xh1, xl1;
      const float* xp = a.x + ((size_t)(t * 32 + mrow) << 10) + ka;
      cvt8(xp, xh0, xl0);
      cvt8(xp + (16 << 10), xh1, xl1);
      bf16x8 ah0 = *(const bf16x8*)(a.hh + mrow * 1024 + ka);
      bf16x8 al0 = *(const bf16x8*)(a.hl + mrow * 1024 + ka);
      bf16x8 ah1 = *(const bf16x8*)(a.hh + (mrow + 16) * 1024 + ka);
      bf16x8 al1 = *(const bf16x8*)(a.hl + (mrow + 16) * 1024 + ka);
      bf16x8 ph0 = *(const bf16x8*)(chp + mrow * 1024 + ka);
      bf16x8 pl0 = *(const bf16x8*)(clp + mrow * 1024 + ka);
      bf16x8 ph1 = *(const bf16x8*)(chp + (mrow + 16) * 1024 + ka);
      bf16x8 pl1 = *(const bf16x8*)(clp + (mrow + 16) * 1024 + ka);
      // x term (3 cross terms), h term (3), c peephole (3)
      acc0 = mfma16(xh0, bxh[ks], acc0);
      acc0 = mfma16(xl0, bxh[ks], acc0);
      acc0 = mfma16(xh0, bxl[ks], acc0);
      acc0 = mfma16(ah0, bhh[ks], acc0);
      acc0 = mfma16(al0, bhh[ks], acc0);
      acc0 = mfma16(ah0, bhl[ks], acc0);
      pc0  = mfma16(ph0, bch[ks], pc0);
      pc0  = mfma16(pl0, bch[ks], pc0);
      pc0  = mfma16(ph0, bcl[ks], pc0);
      acc1 = mfma16(xh1, bxh[ks], acc1);
      acc1 = mfma16(xl1, bxh[ks], acc1);
      acc1 = mfma16(xh1, bxl[ks], acc1);
      acc1 = mfma16(ah1, bhh[ks], acc1);
      acc1 = mfma16(al1, bhh[ks], acc1);
      acc1 = mfma16(ah1, bhl[ks], acc1);
      pc1  = mfma16(ph1, bch[ks], pc1);
      pc1  = mfma16(pl1, bch[ks], pc1);
      pc1  = mfma16(ph1, bcl[ks], pc1);
    }
    {
      const bool take_pc = (col & 3) != 3;   // exclude o-gate peephole (needs c_new)
#pragma unroll
      for (int v = 0; v < 4; ++v) {
        scr[((wave * 2 + 0) * 16 + rq + v) * 16 + col] = acc0[v] + (take_pc ? pc0[v] : 0.f);
        scr[((wave * 2 + 1) * 16 + rq + v) * 16 + col] = acc1[v] + (take_pc ? pc1[v] : 0.f);
      }
    }
    __syncthreads();
    if (tid < 128) {
      float pre[4];
#pragma unroll
      for (int g = 0; g < 4; ++g) {
        float s = 0.f;
#pragma unroll
        for (int w = 0; w < 8; ++w)
          s += scr[((w * 2 + (eb >> 4)) * 16 + (eb & 15)) * 16 + ejj * 4 + g];
        pre[g] = s;
      }
      float iv = 1.f / (1.f + expf(-(pre[0] + bi)));
      float fv = 1.f / (1.f + expf(-(pre[1] + bfv)));
      float cv = tanhf(pre[2] + bcv);
      c_reg = fv * c_reg + iv * cv;           // fp32 carry, owner thread
      u16 chi = f2bf(c_reg);
      chc[eb * 1024 + ej] = chi;
      clc[eb * 1024 + ej] = f2bf(c_reg - bf2f(chi));
      o_pre = pre[3] + bo;
    }
    gbar(a.cnt, (++ep) * gridDim.x);          // c_t visible device-wide

    // ======== phase 2: o-gate peephole = c_t @ W_oc ========
    f32x4 a20 = {}, a21 = {};
#pragma unroll
    for (int ks = 0; ks < 4; ++ks) {
      const int ka = kw + ks * 32 + kq;
      bf16x8 th0 = *(const bf16x8*)(chc + mrow * 1024 + ka);
      bf16x8 tl0 = *(const bf16x8*)(clc + mrow * 1024 + ka);
      bf16x8 th1 = *(const bf16x8*)(chc + (mrow + 16) * 1024 + ka);
      bf16x8 tl1 = *(const bf16x8*)(clc + (mrow + 16) * 1024 + ka);
      a20 = mfma16(th0, bch[ks], a20);
      a20 = mfma16(tl0, bch[ks], a20);
      a20 = mfma16(th0, bcl[ks], a20);
      a21 = mfma16(th1, bch[ks], a21);
      a21 = mfma16(tl1, bch[ks], a21);
      a21 = mfma16(th1, bcl[ks], a21);
    }
#pragma unroll
    for (int v = 0; v < 4; ++v) {
      scr[((wave * 2 + 0) * 16 + rq + v) * 16 + col] = a20[v];
      scr[((wave * 2 + 1) * 16 + rq + v) * 16 + col] = a21[v];
    }
    __syncthreads();
    if (tid < 128) {
      float s = o_pre;
#pragma unroll
      for (int w = 0; w < 8; ++w)
        s += scr[((w * 2 + (eb >> 4)) * 16 + (eb & 15)) * 16 + ejj * 4 + 3];
      float ov = 1.f / (1.f + expf(-s));
      float hv = ov * tanhf(c_reg);
      u16 hhi = f2bf(hv);
      a.hh[eb * 1024 + ej] = hhi;
      a.hl[eb * 1024 + ej] = f2bf(hv - bf2f(hhi));
      if (t == 511) a.out[eb * 1024 + ej] = hv;
    }
    gbar(a.cnt, (++ep) * gridDim.x);          // h_t visible device-wide
  }
}

extern "C" void kernel_launch(void* const* d_in, const int* in_sizes, int n_in,
                              void* d_out, int out_size, void* d_ws, size_t ws_size,
                              hipStream_t stream) {
  (void)in_sizes; (void)n_in; (void)out_size;
  RecArgs ra;
  ra.x    = (const float*)d_in[0];
  ra.W_ix = (const float*)d_in[1];
  ra.W_ih = (const float*)d_in[2];
  ra.W_ic = (const float*)d_in[3];
  ra.W_fx = (const float*)d_in[4];
  ra.W_fh = (const float*)d_in[5];
  ra.W_fc = (const float*)d_in[6];
  ra.W_cx = (const float*)d_in[7];
  ra.W_ch = (const float*)d_in[8];
  ra.W_ox = (const float*)d_in[9];
  ra.W_oh = (const float*)d_in[10];
  ra.W_oc = (const float*)d_in[11];
  ra.b_i  = (const float*)d_in[12];
  ra.b_f  = (const float*)d_in[13];
  ra.b_c  = (const float*)d_in[14];
  ra.b_o  = (const float*)d_in[15];

  char* ws = (char*)d_ws;
  size_t off = 0;
  auto alloc = [&](size_t bytes) {
    char* p = ws + off;
    off = (off + bytes + 255) & ~(size_t)255;
    return p;
  };
  ra.hh  = (u16*)alloc(32 * 1024 * 2);
  ra.hl  = (u16*)alloc(32 * 1024 * 2);
  ra.ch0 = (u16*)alloc(32 * 1024 * 2);
  ra.cl0 = (u16*)alloc(32 * 1024 * 2);
  ra.ch1 = (u16*)alloc(32 * 1024 * 2);
  ra.cl1 = (u16*)alloc(32 * 1024 * 2);
  ra.cnt = (unsigned*)alloc(256);
  ra.out = (float*)d_out;
  if (off > ws_size) return;   // visible failure if ws too small (needs ~0.4MB)

  hipMemsetAsync(ra.cnt, 0, 4, stream);   // reset barrier counter each launch

  void* args[] = {&ra};
  hipError_t e = hipLaunchCooperativeKernel((void*)lstm_rec, dim3(256), dim3(512),
                                            args, 0, stream);
  if (e != hipSuccess) {
    // co-residency still holds: 1 block/CU x 256 blocks on 256 CUs
    lstm_rec<<<dim3(256), dim3(512), 0, stream>>>(ra);
  }
}

// Round 3
// 17615.381 us; speedup vs baseline: 4.9988x; 4.9988x over previous
//
#include <hip/hip_runtime.h>
#include <hip/hip_bf16.h>
#include <stdint.h>

typedef unsigned short u16;
typedef float f32x4 __attribute__((ext_vector_type(4)));
typedef __bf16 bf16x8 __attribute__((ext_vector_type(8)));

__device__ inline u16 f2bf(float f) {
  __bf16 h = (__bf16)f;                 // RTNE
  return __builtin_bit_cast(u16, h);
}
__device__ inline float bf2f(u16 u) {
  unsigned int x = ((unsigned int)u) << 16;
  return __builtin_bit_cast(float, x);
}
__device__ inline f32x4 mfma16(bf16x8 a, bf16x8 b, f32x4 c) {
  return __builtin_amdgcn_mfma_f32_16x16x32_bf16(a, b, c, 0, 0, 0);
}
// split 8 contiguous fp32 into bf16 hi + lo fragments
__device__ inline void cvt8(const float* p, bf16x8& h, bf16x8& l) {
  f32x4 u = *(const f32x4*)p;
  f32x4 v = *(const f32x4*)(p + 4);
#pragma unroll
  for (int i = 0; i < 4; ++i) {
    float a = u[i]; __bf16 ah = (__bf16)a; h[i] = ah; l[i] = (__bf16)(a - (float)ah);
    float b = v[i]; __bf16 bh = (__bf16)b; h[i + 4] = bh; l[i + 4] = (__bf16)(b - (float)bh);
  }
}
// gather 8 k-strided fp32 (stride 1024 floats) into bf16 hi + lo fragments
__device__ inline void gather8(const float* p, bf16x8& h, bf16x8& l) {
#pragma unroll
  for (int e = 0; e < 8; ++e) {
    float f = p[(size_t)e * 1024];
    __bf16 x = (__bf16)f;
    h[e] = x; l[e] = (__bf16)(f - (float)x);
  }
}

struct RecArgs {
  const float* x;
  const float *W_ix, *W_ih, *W_ic, *W_fx, *W_fh, *W_fc, *W_cx, *W_ch;
  const float *W_ox, *W_oh, *W_oc;
  const float *b_i, *b_f, *b_c, *b_o;
  u16 *hh, *hl, *ch0, *cl0, *ch1, *cl1;   // state planes [32][1024] bf16
  unsigned* cnt;
  float* out;
};

// Grid barrier, cheap memory-model edition:
//  - RELAXED poll (no buffer_inv per iteration!)
//  - exactly ONE release fence (buffer_wbl2) before arrive, ONE acquire fence
//    (buffer_inv) after the count is reached — both in thread 0 only.
// __syncthreads drains each wave's vmcnt before s_barrier, so all waves'
// state stores are in L2 before thread 0's wbl2 flushes them to memory-side.
__device__ inline void gbar(unsigned* cnt, unsigned target) {
  __syncthreads();
  if (threadIdx.x == 0) {
    __builtin_amdgcn_fence(__ATOMIC_RELEASE, "agent");   // wbl2: publish state
    __hip_atomic_fetch_add(cnt, 1u, __ATOMIC_RELAXED, __HIP_MEMORY_SCOPE_AGENT);
    int it = 0;
    while (__hip_atomic_load(cnt, __ATOMIC_RELAXED, __HIP_MEMORY_SCOPE_AGENT) < target
           && it < 150000) {
      __builtin_amdgcn_s_sleep(4);
      ++it;
    }
    __builtin_amdgcn_fence(__ATOMIC_ACQUIRE, "agent");   // single buffer_inv
  }
  __syncthreads();
}

// Persistent LSTM: 256 blocks x 512 threads (8 waves). Block owns 4 H-columns
// of each gate (16 gate-cols). Wave w owns K-slice [w*128, w*128+128).
// All weights register-resident as MFMA B-fragments (hi/lo bf16 split).
// Static LDS: 16KB reduce scratch. 2 grid barriers per step (structural:
// dense W_oc needs full c_t; next step needs full h_t).
__global__ __launch_bounds__(512, 2) void lstm_rec(RecArgs a) {
  __shared__ float scr[8 * 2 * 16 * 16];   // [wave][mt][row][col]

  const int tid = threadIdx.x;
  const int wg = blockIdx.x;
  const int j0 = wg * 4;
  const int lane = tid & 63;
  const int wave = tid >> 6;
  const int mrow = lane & 15;               // A-row (batch) lane index
  const int kq = (lane >> 4) * 8;           // k sub-offset within 32
  const int kw = wave * 128;                // per-wave K slice
  const int col = lane & 15;                // B/D column lane index
  const int rq = (lane >> 4) * 4;           // D row quad base

  // ---- one-time: B-fragments (weights) -> registers, hi/lo split ----
  const int fjj = col >> 2, fg = col & 3;   // col = jj*4 + g
  const int fj = j0 + fjj;
  const float* Wx = (fg == 0) ? a.W_ix : (fg == 1) ? a.W_fx : (fg == 2) ? a.W_cx : a.W_ox;
  const float* Wh = (fg == 0) ? a.W_ih : (fg == 1) ? a.W_fh : (fg == 2) ? a.W_ch : a.W_oh;
  const float* Wc = (fg == 0) ? a.W_ic : (fg == 1) ? a.W_fc : (fg == 3) ? a.W_oc : a.W_ic;

  bf16x8 bxh[4], bxl[4], bhh[4], bhl[4], bch[4], bcl[4];
#pragma unroll
  for (int ks = 0; ks < 4; ++ks) {
    const size_t k8 = (size_t)(kw + ks * 32 + kq);
    gather8(Wx + k8 * 1024 + fj, bxh[ks], bxl[ks]);
    gather8(Wh + k8 * 1024 + fj, bhh[ks], bhl[ks]);
    if (fg != 2) {
      gather8(Wc + k8 * 1024 + fj, bch[ks], bcl[ks]);
    } else {
      bf16x8 z = {};
      bch[ks] = z; bcl[ks] = z;
    }
  }

  // ---- zero own slice of state ----
  if (tid < 128) {
    const int b = tid >> 2;
    const int o = b * 1024 + j0 + (tid & 3);
    a.hh[o] = 0; a.hl[o] = 0;
    a.ch0[o] = 0; a.cl0[o] = 0; a.ch1[o] = 0; a.cl1[o] = 0;
  }

  // ---- prefetch x(t=0) fragments (hi/lo bf16) into registers ----
  bf16x8 xh[4][2], xl[4][2];
#pragma unroll
  for (int ks = 0; ks < 4; ++ks) {
    const int ka = kw + ks * 32 + kq;
    const float* xp = a.x + ((size_t)mrow << 10) + ka;
    cvt8(xp, xh[ks][0], xl[ks][0]);
    cvt8(xp + (16 << 10), xh[ks][1], xl[ks][1]);
  }

  unsigned ep = 0;
  gbar(a.cnt, (++ep) * gridDim.x);

  // elementwise thread constants (threads 0..127: b = tid>>2, jj = tid&3)
  const int eb = tid >> 2, ejj = tid & 3, ej = j0 + (tid & 3);
  float bi = 0.f, bfv = 0.f, bcv = 0.f, bo = 0.f;
  if (tid < 128) {
    bi = a.b_i[ej]; bfv = a.b_f[eb * 1024 + ej]; bcv = a.b_c[ej]; bo = a.b_o[ej];
  }
  float c_reg = 0.f, o_pre = 0.f;

  u16* CH[2] = {a.ch0, a.ch1};
  u16* CL[2] = {a.cl0, a.cl1};

  for (int t = 0; t < 512; ++t) {
    u16* chc = CH[t & 1];       u16* clc = CL[t & 1];
    const u16* chp = CH[(t & 1) ^ 1];
    const u16* clp = CL[(t & 1) ^ 1];

    // ======== phase 1: pre-gates = x@Wx + h@Wh (+ c@Wc peephole i,f) ========
    f32x4 acc0 = {}, acc1 = {}, pc0 = {}, pc1 = {};
#pragma unroll
    for (int ks = 0; ks < 4; ++ks) {
      const int ka = kw + ks * 32 + kq;
      bf16x8 ah0 = *(const bf16x8*)(a.hh + mrow * 1024 + ka);
      bf16x8 al0 = *(const bf16x8*)(a.hl + mrow * 1024 + ka);
      bf16x8 ah1 = *(const bf16x8*)(a.hh + (mrow + 16) * 1024 + ka);
      bf16x8 al1 = *(const bf16x8*)(a.hl + (mrow + 16) * 1024 + ka);
      bf16x8 ph0 = *(const bf16x8*)(chp + mrow * 1024 + ka);
      bf16x8 pl0 = *(const bf16x8*)(clp + mrow * 1024 + ka);
      bf16x8 ph1 = *(const bf16x8*)(chp + (mrow + 16) * 1024 + ka);
      bf16x8 pl1 = *(const bf16x8*)(clp + (mrow + 16) * 1024 + ka);
      // x term (3 cross terms), h term (3), c peephole (3)
      acc0 = mfma16(xh[ks][0], bxh[ks], acc0);
      acc0 = mfma16(xl[ks][0], bxh[ks], acc0);
      acc0 = mfma16(xh[ks][0], bxl[ks], acc0);
      acc0 = mfma16(ah0, bhh[ks], acc0);
      acc0 = mfma16(al0, bhh[ks], acc0);
      acc0 = mfma16(ah0, bhl[ks], acc0);
      pc0  = mfma16(ph0, bch[ks], pc0);
      pc0  = mfma16(pl0, bch[ks], pc0);
      pc0  = mfma16(ph0, bcl[ks], pc0);
      acc1 = mfma16(xh[ks][1], bxh[ks], acc1);
      acc1 = mfma16(xl[ks][1], bxh[ks], acc1);
      acc1 = mfma16(xh[ks][1], bxl[ks], acc1);
      acc1 = mfma16(ah1, bhh[ks], acc1);
      acc1 = mfma16(al1, bhh[ks], acc1);
      acc1 = mfma16(ah1, bhl[ks], acc1);
      pc1  = mfma16(ph1, bch[ks], pc1);
      pc1  = mfma16(pl1, bch[ks], pc1);
      pc1  = mfma16(ph1, bcl[ks], pc1);
    }
    {
      const bool take_pc = (col & 3) != 3;   // o-gate peephole deferred to phase 2
#pragma unroll
      for (int v = 0; v < 4; ++v) {
        scr[((wave * 2 + 0) * 16 + rq + v) * 16 + col] = acc0[v] + (take_pc ? pc0[v] : 0.f);
        scr[((wave * 2 + 1) * 16 + rq + v) * 16 + col] = acc1[v] + (take_pc ? pc1[v] : 0.f);
      }
    }
    __syncthreads();
    if (tid < 128) {
      float pre[4];
#pragma unroll
      for (int g = 0; g < 4; ++g) {
        float s = 0.f;
#pragma unroll
        for (int w = 0; w < 8; ++w)
          s += scr[((w * 2 + (eb >> 4)) * 16 + (eb & 15)) * 16 + ejj * 4 + g];
        pre[g] = s;
      }
      float iv = 1.f / (1.f + expf(-(pre[0] + bi)));
      float fv = 1.f / (1.f + expf(-(pre[1] + bfv)));
      float cv = tanhf(pre[2] + bcv);
      c_reg = fv * c_reg + iv * cv;           // fp32 carry, owner thread
      u16 chi = f2bf(c_reg);
      chc[eb * 1024 + ej] = chi;
      clc[eb * 1024 + ej] = f2bf(c_reg - bf2f(chi));
      o_pre = pre[3] + bo;
    }
    gbar(a.cnt, (++ep) * gridDim.x);          // c_t visible device-wide

    // ======== phase 2: o-gate peephole = c_t @ W_oc ========
    f32x4 a20 = {}, a21 = {};
#pragma unroll
    for (int ks = 0; ks < 4; ++ks) {
      const int ka = kw + ks * 32 + kq;
      bf16x8 th0 = *(const bf16x8*)(chc + mrow * 1024 + ka);
      bf16x8 tl0 = *(const bf16x8*)(clc + mrow * 1024 + ka);
      bf16x8 th1 = *(const bf16x8*)(chc + (mrow + 16) * 1024 + ka);
      bf16x8 tl1 = *(const bf16x8*)(clc + (mrow + 16) * 1024 + ka);
      a20 = mfma16(th0, bch[ks], a20);
      a20 = mfma16(tl0, bch[ks], a20);
      a20 = mfma16(th0, bcl[ks], a20);
      a21 = mfma16(th1, bch[ks], a21);
      a21 = mfma16(tl1, bch[ks], a21);
      a21 = mfma16(th1, bcl[ks], a21);
    }
#pragma unroll
    for (int v = 0; v < 4; ++v) {
      scr[((wave * 2 + 0) * 16 + rq + v) * 16 + col] = a20[v];
      scr[((wave * 2 + 1) * 16 + rq + v) * 16 + col] = a21[v];
    }
    __syncthreads();
    if (tid < 128) {
      float s = o_pre;
#pragma unroll
      for (int w = 0; w < 8; ++w)
        s += scr[((w * 2 + (eb >> 4)) * 16 + (eb & 15)) * 16 + ejj * 4 + 3];
      float ov = 1.f / (1.f + expf(-s));
      float hv = ov * tanhf(c_reg);
      u16 hhi = f2bf(hv);
      a.hh[eb * 1024 + ej] = hhi;
      a.hl[eb * 1024 + ej] = f2bf(hv - bf2f(hhi));
      if (t == 511) a.out[eb * 1024 + ej] = hv;
    }
    // ---- prefetch x(t+1): L3 latency hides in the barrier entry/wait ----
    {
      const int tn = (t < 511) ? t + 1 : 511;
#pragma unroll
      for (int ks = 0; ks < 4; ++ks) {
        const int ka = kw + ks * 32 + kq;
        const float* xp = a.x + ((size_t)(tn * 32 + mrow) << 10) + ka;
        cvt8(xp, xh[ks][0], xl[ks][0]);
        cvt8(xp + (16 << 10), xh[ks][1], xl[ks][1]);
      }
    }
    gbar(a.cnt, (++ep) * gridDim.x);          // h_t visible device-wide
  }
}

extern "C" void kernel_launch(void* const* d_in, const int* in_sizes, int n_in,
                              void* d_out, int out_size, void* d_ws, size_t ws_size,
                              hipStream_t stream) {
  (void)in_sizes; (void)n_in; (void)out_size;
  RecArgs ra;
  ra.x    = (const float*)d_in[0];
  ra.W_ix = (const float*)d_in[1];
  ra.W_ih = (const float*)d_in[2];
  ra.W_ic = (const float*)d_in[3];
  ra.W_fx = (const float*)d_in[4];
  ra.W_fh = (const float*)d_in[5];
  ra.W_fc = (const float*)d_in[6];
  ra.W_cx = (const float*)d_in[7];
  ra.W_ch = (const float*)d_in[8];
  ra.W_ox = (const float*)d_in[9];
  ra.W_oh = (const float*)d_in[10];
  ra.W_oc = (const float*)d_in[11];
  ra.b_i  = (const float*)d_in[12];
  ra.b_f  = (const float*)d_in[13];
  ra.b_c  = (const float*)d_in[14];
  ra.b_o  = (const float*)d_in[15];

  char* ws = (char*)d_ws;
  size_t off = 0;
  auto alloc = [&](size_t bytes) {
    char* p = ws + off;
    off = (off + bytes + 255) & ~(size_t)255;
    return p;
  };
  ra.hh  = (u16*)alloc(32 * 1024 * 2);
  ra.hl  = (u16*)alloc(32 * 1024 * 2);
  ra.ch0 = (u16*)alloc(32 * 1024 * 2);
  ra.cl0 = (u16*)alloc(32 * 1024 * 2);
  ra.ch1 = (u16*)alloc(32 * 1024 * 2);
  ra.cl1 = (u16*)alloc(32 * 1024 * 2);
  ra.cnt = (unsigned*)alloc(256);
  ra.out = (float*)d_out;
  if (off > ws_size) return;   // visible failure if ws too small (needs ~0.4MB)

  hipMemsetAsync(ra.cnt, 0, 4, stream);   // reset barrier counter each launch

  void* args[] = {&ra};
  hipError_t e = hipLaunchCooperativeKernel((void*)lstm_rec, dim3(256), dim3(512),
                                            args, 0, stream);
  if (e != hipSuccess) {
    // co-residency still holds: 1 block/CU x 256 blocks on 256 CUs
    lstm_rec<<<dim3(256), dim3(512), 0, stream>>>(ra);
  }
}

// Round 5
// 8262.962 us; speedup vs baseline: 10.6567x; 2.1318x over previous
//
#include <hip/hip_runtime.h>
#include <hip/hip_bf16.h>
#include <stdint.h>

typedef unsigned short u16;
typedef uint32_t u32;
typedef unsigned long long u64;
typedef float f32x4 __attribute__((ext_vector_type(4)));
typedef __bf16 bf16x8 __attribute__((ext_vector_type(8)));

__device__ inline u16 f2bf(float f) {
  __bf16 h = (__bf16)f;                 // RTNE
  return __builtin_bit_cast(u16, h);
}
__device__ inline float bf2f(u16 u) {
  u32 x = ((u32)u) << 16;
  return __builtin_bit_cast(float, x);
}
__device__ inline f32x4 mfma16(bf16x8 a, bf16x8 b, f32x4 c) {
  return __builtin_amdgcn_mfma_f32_16x16x32_bf16(a, b, c, 0, 0, 0);
}
// split 8 contiguous fp32 into bf16 hi + lo fragments (cached loads)
__device__ inline void cvt8(const float* p, bf16x8& h, bf16x8& l) {
  f32x4 u = *(const f32x4*)p;
  f32x4 v = *(const f32x4*)(p + 4);
#pragma unroll
  for (int i = 0; i < 4; ++i) {
    float a = u[i]; __bf16 ah = (__bf16)a; h[i] = ah; l[i] = (__bf16)(a - (float)ah);
    float b = v[i]; __bf16 bh = (__bf16)b; h[i + 4] = bh; l[i + 4] = (__bf16)(b - (float)bh);
  }
}
// gather 8 k-strided fp32 (stride 1024 floats) into bf16 hi + lo fragments
__device__ inline void gather8(const float* p, bf16x8& h, bf16x8& l) {
#pragma unroll
  for (int e = 0; e < 8; ++e) {
    float f = p[(size_t)e * 1024];
    __bf16 x = (__bf16)f;
    h[e] = x; l[e] = (__bf16)(f - (float)x);
  }
}

// ---- coherence-point (bypass) state accessors: no fences needed anywhere ----
__device__ inline u64 ld64(const u64* p) {
  return __hip_atomic_load(p, __ATOMIC_RELAXED, __HIP_MEMORY_SCOPE_AGENT);
}
__device__ inline void st32(u32* p, u32 v) {
  __hip_atomic_store(p, v, __ATOMIC_RELAXED, __HIP_MEMORY_SCOPE_AGENT);
}
// word = hi_bf16 | lo_bf16<<16 ; split u64 (2 words) into hi-pair / lo-pair
// (plain u32 out-params — compile-time-indexed arrays stay in registers)
struct U32Pair { u32 h, l; };
__device__ inline U32Pair unpack2(u64 w) {
  u32 a0 = (u32)w, a1 = (u32)(w >> 32);
  U32Pair r;
  r.h = __builtin_amdgcn_perm(a1, a0, 0x05040100);   // low16 of each word
  r.l = __builtin_amdgcn_perm(a1, a0, 0x07060302);   // high16 of each word
  return r;
}
__device__ inline void unpack_frag(u64 w0, u64 w1, u64 w2, u64 w3,
                                   bf16x8& fh, bf16x8& fl) {
  u32 H[4], L[4];
  U32Pair p0 = unpack2(w0); H[0] = p0.h; L[0] = p0.l;
  U32Pair p1 = unpack2(w1); H[1] = p1.h; L[1] = p1.l;
  U32Pair p2 = unpack2(w2); H[2] = p2.h; L[2] = p2.l;
  U32Pair p3 = unpack2(w3); H[3] = p3.h; L[3] = p3.l;
  struct W4 { u32 w[4]; };
  W4 hh = {{H[0], H[1], H[2], H[3]}};
  W4 ll = {{L[0], L[1], L[2], L[3]}};
  fh = __builtin_bit_cast(bf16x8, hh);
  fl = __builtin_bit_cast(bf16x8, ll);
}
// swizzled state layout: u32 index of element (b, j), plane = [32][1024]
// [q:j>>5]<<10 | [half:b>>4]<<9 | [epair:(j>>1)&3]<<7 | [kgroup:(j>>3)&3]<<5
// | [mrow:b&15]<<1 | [e0:j&1]   -> wave-instr bypass loads are 512B contiguous
__device__ inline u32 swz(int b, int j) {
  return ((u32)(j >> 5) << 10) | ((u32)(b >> 4) << 9) | ((u32)((j >> 1) & 3) << 7)
       | ((u32)((j >> 3) & 3) << 5) | ((u32)(b & 15) << 1) | (u32)(j & 1);
}

struct RecArgs {
  const float* x;
  const float *W_ix, *W_ih, *W_ic, *W_fx, *W_fh, *W_fc, *W_cx, *W_ch;
  const float *W_ox, *W_oh, *W_oc;
  const float *b_i, *b_f, *b_c, *b_o;
  u32 *hP, *cP;          // packed hi|lo state planes, swizzled, 128KB each
  unsigned* cnt;
  float* out;
};

// Fence-free grid barrier: state stores/loads bypass caches (agent-scope
// relaxed atomics), so plain relaxed add + relaxed poll suffices.
__device__ inline void gbar(unsigned* cnt, unsigned target) {
  __syncthreads();                     // drains vmcnt: bypass stores are at L3
  if (threadIdx.x == 0) {
    __hip_atomic_fetch_add(cnt, 1u, __ATOMIC_RELAXED, __HIP_MEMORY_SCOPE_AGENT);
    int it = 0;
    while (__hip_atomic_load(cnt, __ATOMIC_RELAXED, __HIP_MEMORY_SCOPE_AGENT) < target
           && it < 400000) {
      __builtin_amdgcn_s_sleep(2);
      ++it;
    }
  }
  __syncthreads();
}

// Persistent LSTM: 256 blocks x 512 threads (8 waves). Block owns 4 H-columns
// of each gate. Wave w owns K-slice [w*128, w*128+128). Weights in registers
// (hi/lo bf16 MFMA B-frags). State via coherence-point bypass ops -> no cache
// fences. 2 grid barriers per step (structural).
__global__ __launch_bounds__(512, 2) void lstm_rec(RecArgs a) {
  __shared__ float scr[8 * 2 * 16 * 16];   // [wave][mt][row][col]

  const int tid = threadIdx.x;
  const int wg = blockIdx.x;
  const int j0 = wg * 4;
  const int lane = tid & 63;
  const int wave = tid >> 6;
  const int mrow = lane & 15;               // A-row (batch) lane index
  const int kgroup = lane >> 4;             // k sub-block 0..3
  const int kq = kgroup * 8;
  const int kw = wave * 128;                // per-wave K slice
  const int col = lane & 15;                // B/D column lane index
  const int rq = (lane >> 4) * 4;           // D row quad base
  const int fbase = (kgroup << 4) | mrow;   // per-lane swizzle base (u64 idx)

  const u64* H64 = (const u64*)a.hP;
  const u64* C64 = (const u64*)a.cP;

  // ---- one-time: B-fragments (weights) -> registers, hi/lo split ----
  const int fjj = col >> 2, fg = col & 3;   // col = jj*4 + g
  const int fj = j0 + fjj;
  const float* Wx = (fg == 0) ? a.W_ix : (fg == 1) ? a.W_fx : (fg == 2) ? a.W_cx : a.W_ox;
  const float* Wh = (fg == 0) ? a.W_ih : (fg == 1) ? a.W_fh : (fg == 2) ? a.W_ch : a.W_oh;
  const float* Wc = (fg == 0) ? a.W_ic : (fg == 1) ? a.W_fc : (fg == 3) ? a.W_oc : a.W_ic;

  bf16x8 bxh[4], bxl[4], bhh[4], bhl[4], bch[4], bcl[4];
#pragma unroll
  for (int ks = 0; ks < 4; ++ks) {
    const size_t k8 = (size_t)(kw + ks * 32 + kq);
    gather8(Wx + k8 * 1024 + fj, bxh[ks], bxl[ks]);
    gather8(Wh + k8 * 1024 + fj, bhh[ks], bhl[ks]);
    if (fg != 2) {
      gather8(Wc + k8 * 1024 + fj, bch[ks], bcl[ks]);
    } else {
      bf16x8 z = {};
      bch[ks] = z; bcl[ks] = z;
    }
  }

  // elementwise thread constants (threads 0..127: b = tid>>2, jj = tid&3)
  const int eb = tid >> 2, ejj = tid & 3, ej = j0 + (tid & 3);
  const u32 sidx = swz(eb, ej);
  // ---- zero own slice of state (bypass stores) ----
  if (tid < 128) {
    st32(a.hP + sidx, 0u);
    st32(a.cP + sidx, 0u);
  }
  float bi = 0.f, bfv = 0.f, bcv = 0.f, bo = 0.f;
  if (tid < 128) {
    bi = a.b_i[ej]; bfv = a.b_f[eb * 1024 + ej]; bcv = a.b_c[ej]; bo = a.b_o[ej];
  }
  unsigned ep = 0;
  gbar(a.cnt, (++ep) * gridDim.x);

  float c_reg = 0.f, o_pre = 0.f;
  // carried c_{t-1} fragments (phase2(t-1) loads reused as phase1(t) peephole A)
  bf16x8 cfh0[4] = {}, cfl0[4] = {}, cfh1[4] = {}, cfl1[4] = {};

  for (int t = 0; t < 512; ++t) {
    // ======== phase 1: pre-gates = x@Wx + h@Wh (+ c_{t-1}@Wc peephole) ========
    f32x4 acc0 = {}, acc1 = {}, pc0 = {}, pc1 = {};
#pragma unroll
    for (int ks = 0; ks < 4; ++ks) {
      const int ka = kw + ks * 32 + kq;
      const int ib = (((wave << 2) + ks) << 9) | fbase;
      // h_{t-1} fragments: coalesced bypass loads + perm-unpack
      u64 h00 = ld64(H64 + ib),             h01v = ld64(H64 + ib + (1 << 6));
      u64 h02 = ld64(H64 + ib + (2 << 6)),  h03  = ld64(H64 + ib + (3 << 6));
      u64 h10 = ld64(H64 + ib + (1 << 8)),  h11  = ld64(H64 + ib + (1 << 8) + (1 << 6));
      u64 h12 = ld64(H64 + ib + (1 << 8) + (2 << 6));
      u64 h13 = ld64(H64 + ib + (1 << 8) + (3 << 6));
      bf16x8 ah0, al0, ah1, al1;
      unpack_frag(h00, h01v, h02, h03, ah0, al0);
      unpack_frag(h10, h11, h12, h13, ah1, al1);
      // x fragments (cached, L2-resident)
      bf16x8 xh0, xl0, xh1, xl1;
      const float* xp = a.x + ((size_t)(t * 32 + mrow) << 10) + ka;
      cvt8(xp, xh0, xl0);
      cvt8(xp + (16 << 10), xh1, xl1);
      // x term (3 cross), h term (3), c peephole from carried frags (3)
      acc0 = mfma16(xh0, bxh[ks], acc0);
      acc0 = mfma16(xl0, bxh[ks], acc0);
      acc0 = mfma16(xh0, bxl[ks], acc0);
      acc0 = mfma16(ah0, bhh[ks], acc0);
      acc0 = mfma16(al0, bhh[ks], acc0);
      acc0 = mfma16(ah0, bhl[ks], acc0);
      pc0  = mfma16(cfh0[ks], bch[ks], pc0);
      pc0  = mfma16(cfl0[ks], bch[ks], pc0);
      pc0  = mfma16(cfh0[ks], bcl[ks], pc0);
      acc1 = mfma16(xh1, bxh[ks], acc1);
      acc1 = mfma16(xl1, bxh[ks], acc1);
      acc1 = mfma16(xh1, bxl[ks], acc1);
      acc1 = mfma16(ah1, bhh[ks], acc1);
      acc1 = mfma16(al1, bhh[ks], acc1);
      acc1 = mfma16(ah1, bhl[ks], acc1);
      pc1  = mfma16(cfh1[ks], bch[ks], pc1);
      pc1  = mfma16(cfl1[ks], bch[ks], pc1);
      pc1  = mfma16(cfh1[ks], bcl[ks], pc1);
    }
    {
      const bool take_pc = (col & 3) != 3;   // o-gate peephole deferred to phase 2
#pragma unroll
      for (int v = 0; v < 4; ++v) {
        scr[((wave * 2 + 0) * 16 + rq + v) * 16 + col] = acc0[v] + (take_pc ? pc0[v] : 0.f);
        scr[((wave * 2 + 1) * 16 + rq + v) * 16 + col] = acc1[v] + (take_pc ? pc1[v] : 0.f);
      }
    }
    __syncthreads();
    if (tid < 128) {
      float pre[4];
#pragma unroll
      for (int g = 0; g < 4; ++g) {
        float s = 0.f;
#pragma unroll
        for (int w = 0; w < 8; ++w)
          s += scr[((w * 2 + (eb >> 4)) * 16 + (eb & 15)) * 16 + ejj * 4 + g];
        pre[g] = s;
      }
      float iv = 1.f / (1.f + expf(-(pre[0] + bi)));
      float fv = 1.f / (1.f + expf(-(pre[1] + bfv)));
      float cv = tanhf(pre[2] + bcv);
      c_reg = fv * c_reg + iv * cv;           // fp32 carry, owner thread
      u16 chi = f2bf(c_reg);
      u16 clo = f2bf(c_reg - bf2f(chi));
      st32(a.cP + sidx, (u32)chi | ((u32)clo << 16));
      o_pre = pre[3] + bo;
    }
    gbar(a.cnt, (++ep) * gridDim.x);          // c_t visible device-wide

    // ======== phase 2: o-gate peephole = c_t @ W_oc ========
    f32x4 a20 = {}, a21 = {};
#pragma unroll
    for (int ks = 0; ks < 4; ++ks) {
      const int ib = (((wave << 2) + ks) << 9) | fbase;
      u64 c00 = ld64(C64 + ib),             c01v = ld64(C64 + ib + (1 << 6));
      u64 c02 = ld64(C64 + ib + (2 << 6)),  c03  = ld64(C64 + ib + (3 << 6));
      u64 c10 = ld64(C64 + ib + (1 << 8)),  c11  = ld64(C64 + ib + (1 << 8) + (1 << 6));
      u64 c12 = ld64(C64 + ib + (1 << 8) + (2 << 6));
      u64 c13 = ld64(C64 + ib + (1 << 8) + (3 << 6));
      unpack_frag(c00, c01v, c02, c03, cfh0[ks], cfl0[ks]);   // save as carry
      unpack_frag(c10, c11, c12, c13, cfh1[ks], cfl1[ks]);
      a20 = mfma16(cfh0[ks], bch[ks], a20);
      a20 = mfma16(cfl0[ks], bch[ks], a20);
      a20 = mfma16(cfh0[ks], bcl[ks], a20);
      a21 = mfma16(cfh1[ks], bch[ks], a21);
      a21 = mfma16(cfl1[ks], bch[ks], a21);
      a21 = mfma16(cfh1[ks], bcl[ks], a21);
    }
#pragma unroll
    for (int v = 0; v < 4; ++v) {
      scr[((wave * 2 + 0) * 16 + rq + v) * 16 + col] = a20[v];
      scr[((wave * 2 + 1) * 16 + rq + v) * 16 + col] = a21[v];
    }
    __syncthreads();
    if (tid < 128) {
      float s = o_pre;
#pragma unroll
      for (int w = 0; w < 8; ++w)
        s += scr[((w * 2 + (eb >> 4)) * 16 + (eb & 15)) * 16 + ejj * 4 + 3];
      float ov = 1.f / (1.f + expf(-s));
      float hv = ov * tanhf(c_reg);
      u16 hhi = f2bf(hv);
      u16 hlo = f2bf(hv - bf2f(hhi));
      st32(a.hP + sidx, (u32)hhi | ((u32)hlo << 16));
      if (t == 511) a.out[eb * 1024 + ej] = hv;
    }
    gbar(a.cnt, (++ep) * gridDim.x);          // h_t visible device-wide
  }
}

extern "C" void kernel_launch(void* const* d_in, const int* in_sizes, int n_in,
                              void* d_out, int out_size, void* d_ws, size_t ws_size,
                              hipStream_t stream) {
  (void)in_sizes; (void)n_in; (void)out_size;
  RecArgs ra;
  ra.x    = (const float*)d_in[0];
  ra.W_ix = (const float*)d_in[1];
  ra.W_ih = (const float*)d_in[2];
  ra.W_ic = (const float*)d_in[3];
  ra.W_fx = (const float*)d_in[4];
  ra.W_fh = (const float*)d_in[5];
  ra.W_fc = (const float*)d_in[6];
  ra.W_cx = (const float*)d_in[7];
  ra.W_ch = (const float*)d_in[8];
  ra.W_ox = (const float*)d_in[9];
  ra.W_oh = (const float*)d_in[10];
  ra.W_oc = (const float*)d_in[11];
  ra.b_i  = (const float*)d_in[12];
  ra.b_f  = (const float*)d_in[13];
  ra.b_c  = (const float*)d_in[14];
  ra.b_o  = (const float*)d_in[15];

  char* ws = (char*)d_ws;
  size_t off = 0;
  auto alloc = [&](size_t bytes) {
    char* p = ws + off;
    off = (off + bytes + 255) & ~(size_t)255;
    return p;
  };
  ra.hP  = (u32*)alloc(32 * 1024 * 4);   // packed h (hi|lo), swizzled
  ra.cP  = (u32*)alloc(32 * 1024 * 4);   // packed c (hi|lo), swizzled
  ra.cnt = (unsigned*)alloc(256);
  ra.out = (float*)d_out;
  if (off > ws_size) return;             // visible failure if ws too small

  (void)hipMemsetAsync(ra.cnt, 0, 4, stream);  // reset barrier counter

  void* args[] = {&ra};
  hipError_t e = hipLaunchCooperativeKernel((void*)lstm_rec, dim3(256), dim3(512),
                                            args, 0, stream);
  if (e != hipSuccess) {
    // co-residency still holds: 1 block/CU x 256 blocks on 256 CUs
    lstm_rec<<<dim3(256), dim3(512), 0, stream>>>(ra);
  }
}